// Round 3
// baseline (90.287 us; speedup 1.0000x reference)
//
#include <hip/hip_runtime.h>

typedef __attribute__((ext_vector_type(8))) short short8;   // 8 bf16 (4 VGPRs)
typedef __attribute__((ext_vector_type(4))) float f32x4;    // 4 fp32 acc

#define CTX 32
#define ND  64
#define NH  64
#define LOG2E_8 11.541560327111707f   // 8 * log2(e), folded into M

// ---- per-wave LDS layout (bytes) ----
//   rtH [32][40] @0 (2560), rtL @2560 (2560)   -- tmp half-tile round-trip, stride 80 B
//   vT  [64][40] @0 (5120)                     -- aliases rtH+rtL (dead after P)
//   P   [32][32] @5120 (2048)                  -- unpadded, stride 64 B
#define PWSTR 80
#define PW_RTH 0
#define PW_RTL 2560
#define PW_VT  0
#define PW_P   5120
#define WAVE_BYTES 7168
#define LDS_BYTES (4 * WAVE_BYTES)   // 28672 -> 5 WG/CU (20 waves, 62%)

__device__ __forceinline__ unsigned short f2bf(float f) {
  unsigned int u = __builtin_bit_cast(unsigned int, f);
  u += 0x7FFFu + ((u >> 16) & 1u);     // RNE
  return (unsigned short)(u >> 16);
}
__device__ __forceinline__ float bf2f(unsigned short b) {
  unsigned int u = ((unsigned int)b) << 16;
  return __builtin_bit_cast(float, u);
}

#define MFMA(a, b, c) __builtin_amdgcn_mfma_f32_16x16x32_bf16((a), (b), (c), 0, 0, 0)

// ---- precompute Mt = (Wq Wk^T)^T * 8*log2(e) (bf16 hi/lo) and WvT (bf16), into ws ----
__global__ __launch_bounds__(256) void mk_m(
    const float* __restrict__ Wq, const float* __restrict__ Wk,
    const float* __restrict__ Wv,
    unsigned short* __restrict__ MtH, unsigned short* __restrict__ MtL,
    unsigned short* __restrict__ WvT)
{
  const int idx = blockIdx.x * 256 + threadIdx.x;   // [0,4096): idx = dp*64 + d
  const int dp = idx >> 6, d = idx & 63;
  const float* wq = Wq + d * 64;
  const float* wk = Wk + dp * 64;
  float acc = 0.f;
  #pragma unroll
  for (int h = 0; h < 64; ++h) acc = fmaf(wq[h], wk[h], acc);
  acc *= LOG2E_8;
  const unsigned short hi = f2bf(acc);
  MtH[idx] = hi;
  MtL[idx] = f2bf(acc - bf2f(hi));
  // WvT[h][d] = Wv[d][h]; here (dp,d) -> WvT[dp*64+d] = Wv[d*64+dp]
  WvT[idx] = f2bf(Wv[d * 64 + dp]);
}

__global__ __launch_bounds__(256, 5) void head_fused(
    const float* __restrict__ x,
    const unsigned short* __restrict__ MtH, const unsigned short* __restrict__ MtL,
    const unsigned short* __restrict__ WvT,
    float* __restrict__ out)
{
  __shared__ __align__(16) char lds[LDS_BYTES];
  const int tid = threadIdx.x;

  const int wid  = tid >> 6;
  const int lane = tid & 63;
  const int c = lane & 15;
  const int g = lane >> 4;
  char* const wl = lds + wid * WAVE_BYTES;

  const long b = (long)blockIdx.x * 4 + wid;
  const float* const xb = x + b * (CTX * ND);

  // ---- x -> A-fragments hi/lo. A[lane&15][8*(lane>>4)+j] ----
  short8 xh[2][2], xl[2][2];
  #pragma unroll
  for (int mt = 0; mt < 2; ++mt) {
    #pragma unroll
    for (int kt = 0; kt < 2; ++kt) {
      const float* p = xb + (16 * mt + c) * ND + 32 * kt + 8 * g;
      const f32x4 a0 = *(const f32x4*)(p);
      const f32x4 a1 = *(const f32x4*)(p + 4);
      short8 hi, lo;
      #pragma unroll
      for (int j = 0; j < 4; ++j) {
        const unsigned short h0 = f2bf(a0[j]);
        hi[j] = (short)h0;
        lo[j] = (short)f2bf(a0[j] - bf2f(h0));
        const unsigned short h1 = f2bf(a1[j]);
        hi[4 + j] = (short)h1;
        lo[4 + j] = (short)f2bf(a1[j] - bf2f(h1));
      }
      xh[mt][kt] = hi;
      xl[mt][kt] = lo;
    }
  }

  // ---- tmp = X·Mt (3-term), interleaved per 32-col half with P += tmp·X^T ----
  f32x4 pa[2][2] = {{{0.f,0.f,0.f,0.f},{0.f,0.f,0.f,0.f}},
                    {{0.f,0.f,0.f,0.f},{0.f,0.f,0.f,0.f}}};
  #pragma unroll
  for (int kt = 0; kt < 2; ++kt) {
    #pragma unroll
    for (int ntl = 0; ntl < 2; ++ntl) {
      const int nt = 2 * kt + ntl;
      f32x4 a0 = {0.f, 0.f, 0.f, 0.f};
      f32x4 a1 = {0.f, 0.f, 0.f, 0.f};
      #pragma unroll
      for (int kk = 0; kk < 2; ++kk) {
        // B-frag: Mt[16nt+c][32kk + 8g + j], 16B contiguous, L1-hot (8 KB tile)
        const int eoff = (16 * nt + c) * 64 + 32 * kk + 8 * g;
        const short8 bh = *(const short8*)(MtH + eoff);
        const short8 bl = *(const short8*)(MtL + eoff);
        a0 = MFMA(xh[0][kk], bh, a0);
        a0 = MFMA(xh[0][kk], bl, a0);
        a0 = MFMA(xl[0][kk], bh, a0);
        a1 = MFMA(xh[1][kk], bh, a1);
        a1 = MFMA(xh[1][kk], bl, a1);
        a1 = MFMA(xl[1][kk], bh, a1);
      }
      // D-frag: row = 4g+j (+16), col = c (+16*ntl within rt). Store hi/lo.
      #pragma unroll
      for (int j = 0; j < 4; ++j) {
        const int col2 = 2 * (16 * ntl + c);
        const int off0 = (4 * g + j) * PWSTR + col2;
        const int off1 = (16 + 4 * g + j) * PWSTR + col2;
        const unsigned short h0 = f2bf(a0[j]);
        *(unsigned short*)(wl + PW_RTH + off0) = h0;
        *(unsigned short*)(wl + PW_RTL + off0) = f2bf(a0[j] - bf2f(h0));
        const unsigned short h1 = f2bf(a1[j]);
        *(unsigned short*)(wl + PW_RTH + off1) = h1;
        *(unsigned short*)(wl + PW_RTL + off1) = f2bf(a1[j] - bf2f(h1));
      }
    }
    // read tmp back as A-frags (same wave wrote -> in-order DS, no barrier)
    short8 tH[2], tL[2];
    #pragma unroll
    for (int i = 0; i < 2; ++i) {
      const int off = (16 * i + c) * PWSTR + 16 * g;
      tH[i] = *(const short8*)(wl + PW_RTH + off);
      tL[i] = *(const short8*)(wl + PW_RTL + off);
    }
    // B-operand for tmp·X^T over k=d in [32kt,32kt+32) is x's A-frag at kt
    #pragma unroll
    for (int mt = 0; mt < 2; ++mt) {
      #pragma unroll
      for (int nt2 = 0; nt2 < 2; ++nt2) {
        pa[mt][nt2] = MFMA(tH[mt], xh[nt2][kt], pa[mt][nt2]);
        pa[mt][nt2] = MFMA(tH[mt], xl[nt2][kt], pa[mt][nt2]);
        pa[mt][nt2] = MFMA(tL[mt], xh[nt2][kt], pa[mt][nt2]);
      }
    }
  }

  // ---- causal mask + softmax (log2-domain; scale pre-folded into M) ----
  char* const pbuf = wl + PW_P;
  #pragma unroll
  for (int mt = 0; mt < 2; ++mt) {
    #pragma unroll
    for (int j = 0; j < 4; ++j) {
      const int t = 16 * mt + 4 * g + j;
      float v0 = pa[mt][0][j];              // s = c
      float v1 = pa[mt][1][j];              // s = 16 + c
      if (c > t)      v0 = -__builtin_inff();
      if (16 + c > t) v1 = -__builtin_inff();
      float m = fmaxf(v0, v1);
      m = fmaxf(m, __shfl_xor(m, 1));
      m = fmaxf(m, __shfl_xor(m, 2));
      m = fmaxf(m, __shfl_xor(m, 4));
      m = fmaxf(m, __shfl_xor(m, 8));
      const float e0 = exp2f(v0 - m);
      const float e1 = exp2f(v1 - m);
      float s = e0 + e1;
      s += __shfl_xor(s, 1);
      s += __shfl_xor(s, 2);
      s += __shfl_xor(s, 4);
      s += __shfl_xor(s, 8);
      const float r = 1.0f / s;
      *(unsigned short*)(pbuf + t * 64 + 2 * c)        = f2bf(e0 * r);
      *(unsigned short*)(pbuf + t * 64 + 32 + 2 * c)   = f2bf(e1 * r);
    }
  }

  // ---- v = X·Wv (single term), stored transposed vT[h][s] (aliases rt) ----
  #pragma unroll
  for (int nt = 0; nt < 4; ++nt) {
    f32x4 a0 = {0.f, 0.f, 0.f, 0.f};
    f32x4 a1 = {0.f, 0.f, 0.f, 0.f};
    #pragma unroll
    for (int kk = 0; kk < 2; ++kk) {
      const int eoff = (16 * nt + c) * 64 + 32 * kk + 8 * g;
      const short8 bv = *(const short8*)(WvT + eoff);
      a0 = MFMA(xh[0][kk], bv, a0);
      a1 = MFMA(xh[1][kk], bv, a1);
    }
    #pragma unroll
    for (int j = 0; j < 4; ++j) {
      char* const vrow = wl + PW_VT + (16 * nt + c) * PWSTR;
      *(unsigned short*)(vrow + 2 * (4 * g + j))      = f2bf(a0[j]);
      *(unsigned short*)(vrow + 2 * (16 + 4 * g + j)) = f2bf(a1[j]);
    }
  }

  // ---- PV: out = P·V (K = 32, one MFMA per tile) ----
  const short8 ap0 = *(const short8*)(pbuf + c * 64 + 16 * g);
  const short8 ap1 = *(const short8*)(pbuf + (16 + c) * 64 + 16 * g);
  float* const ob = out + b * (CTX * NH);
  #pragma unroll
  for (int nt = 0; nt < 4; ++nt) {
    const short8 bv = *(const short8*)(wl + PW_VT + (16 * nt + c) * PWSTR + 16 * g);
    f32x4 o0 = {0.f, 0.f, 0.f, 0.f};
    f32x4 o1 = {0.f, 0.f, 0.f, 0.f};
    o0 = MFMA(ap0, bv, o0);
    o1 = MFMA(ap1, bv, o1);
    #pragma unroll
    for (int j = 0; j < 4; ++j) {
      ob[(4 * g + j) * NH + 16 * nt + c]      = o0[j];
      ob[(16 + 4 * g + j) * NH + 16 * nt + c] = o1[j];
    }
  }
}

extern "C" void kernel_launch(void* const* d_in, const int* in_sizes, int n_in,
                              void* d_out, int out_size, void* d_ws, size_t ws_size,
                              hipStream_t stream) {
  // setup_inputs order: x, Wk, Wq, Wv  (all fp32)
  const float* x  = (const float*)d_in[0];
  const float* Wk = (const float*)d_in[1];
  const float* Wq = (const float*)d_in[2];
  const float* Wv = (const float*)d_in[3];
  float* out = (float*)d_out;

  unsigned short* MtH = (unsigned short*)d_ws;          // [64][64] bf16
  unsigned short* MtL = MtH + 64 * 64;
  unsigned short* WvT = MtL + 64 * 64;

  mk_m<<<dim3(16), dim3(256), 0, stream>>>(Wq, Wk, Wv, MtH, MtL, WvT);

  const int batch = in_sizes[0] / (CTX * ND);           // 16384
  head_fused<<<dim3(batch / 4), dim3(256), 0, stream>>>(x, MtH, MtL, WvT, out);
}

// Round 4
// 59.448 us; speedup vs baseline: 1.5188x; 1.5188x over previous
//
#include <hip/hip_runtime.h>

typedef __attribute__((ext_vector_type(8))) short short8;   // 8 bf16 (4 VGPRs)
typedef __attribute__((ext_vector_type(4))) float f32x4;    // 4 fp32
typedef __attribute__((ext_vector_type(2))) unsigned int u32x2;

#define CTX 32
#define ND  64
#define NH  64
#define LOG2E_8 11.541560327111707f   // 8 * log2(e), folded into M
#define NB_PER_WAVE 2

// ---- LDS layout (bytes) ----
// Shared weight tiles, 128 B rows, XOR-swizzled (16B block ^ (row&7))
#define OFF_MH 0                 // MtH [64][64] bf16
#define OFF_ML 8192              // MtL
#define OFF_WV 16384             // WvT [64][64] bf16  (WvT[h][d] = Wv[d][h])
#define OFF_WAVE 24576
// per-wave region:
//   rtH [32][40] @0 (2560), rtL @2560 (2560)   -- tmp round-trip, stride 80 B
//   vT  [64][40] @0 (5120)                     -- aliases rtH+rtL (dead after P^T)
//   P   [32][32] @5120 (2048)                  -- stride 64 B
#define PWSTR 80
#define PW_RTH 0
#define PW_RTL 2560
#define PW_VT  0
#define PW_P   5120
#define WAVE_BYTES 7168
#define LDS_BYTES (OFF_WAVE + 4 * WAVE_BYTES)   // 53248 -> 3 WG/CU

__device__ __forceinline__ unsigned short f2bf(float f) {
  unsigned int u = __builtin_bit_cast(unsigned int, f);
  u += 0x7FFFu + ((u >> 16) & 1u);     // RNE
  return (unsigned short)(u >> 16);
}
__device__ __forceinline__ float bf2f(unsigned short b) {
  unsigned int u = ((unsigned int)b) << 16;
  return __builtin_bit_cast(float, u);
}
__device__ __forceinline__ unsigned int pk2(float a, float b) {
  return (unsigned int)f2bf(a) | ((unsigned int)f2bf(b) << 16);
}

#define MFMA(a, b, c) __builtin_amdgcn_mfma_f32_16x16x32_bf16((a), (b), (c), 0, 0, 0)

// ---- precompute Mt = (Wq Wk^T)^T * 8*log2(e) (bf16 hi/lo) and WvT (bf16), into ws ----
__global__ __launch_bounds__(256) void mk_m(
    const float* __restrict__ Wq, const float* __restrict__ Wk,
    const float* __restrict__ Wv,
    unsigned short* __restrict__ MtH, unsigned short* __restrict__ MtL,
    unsigned short* __restrict__ WvT)
{
  const int idx = blockIdx.x * 256 + threadIdx.x;   // [0,4096): idx = dp*64 + d
  const int dp = idx >> 6, d = idx & 63;
  const float* wq = Wq + d * 64;
  const float* wk = Wk + dp * 64;
  float acc = 0.f;
  #pragma unroll
  for (int h = 0; h < 64; ++h) acc = fmaf(wq[h], wk[h], acc);
  acc *= LOG2E_8;
  const unsigned short hi = f2bf(acc);
  MtH[idx] = hi;
  MtL[idx] = f2bf(acc - bf2f(hi));
  WvT[idx] = f2bf(Wv[d * 64 + dp]);   // WvT[h=dp][d]
}

__device__ __forceinline__ void load_x(const float* __restrict__ xb,
                                       f32x4 (&xr)[2][2][2], int c, int g) {
  #pragma unroll
  for (int mt = 0; mt < 2; ++mt)
    #pragma unroll
    for (int kt = 0; kt < 2; ++kt) {
      const float* p = xb + (16 * mt + c) * ND + 32 * kt + 8 * g;
      xr[mt][kt][0] = *(const f32x4*)(p);
      xr[mt][kt][1] = *(const f32x4*)(p + 4);
    }
}

__device__ __forceinline__ void compute_batch(
    const f32x4 (&xr)[2][2][2], char* lds, char* wl,
    float* __restrict__ ob, int c, int g)
{
  // ---- split x -> A-frags hi/lo. A[lane&15][8*(lane>>4)+j] ----
  short8 xh[2][2], xl[2][2];
  #pragma unroll
  for (int mt = 0; mt < 2; ++mt) {
    #pragma unroll
    for (int kt = 0; kt < 2; ++kt) {
      short8 hi, lo;
      #pragma unroll
      for (int half = 0; half < 2; ++half) {
        #pragma unroll
        for (int j = 0; j < 4; ++j) {
          const float f = xr[mt][kt][half][j];
          const unsigned short h = f2bf(f);
          hi[4 * half + j] = (short)h;
          lo[4 * half + j] = (short)f2bf(f - bf2f(h));
        }
      }
      xh[mt][kt] = hi;
      xl[mt][kt] = lo;
    }
  }

  // ---- tmp = X·Mt (3-term) per 32-col half, then P^T += X·tmp^T ----
  f32x4 pa[2][2] = {{{0.f,0.f,0.f,0.f},{0.f,0.f,0.f,0.f}},
                    {{0.f,0.f,0.f,0.f},{0.f,0.f,0.f,0.f}}};
  #pragma unroll
  for (int kt = 0; kt < 2; ++kt) {
    #pragma unroll
    for (int ntl = 0; ntl < 2; ++ntl) {
      const int nt = 2 * kt + ntl;
      f32x4 a0 = {0.f, 0.f, 0.f, 0.f};
      f32x4 a1 = {0.f, 0.f, 0.f, 0.f};
      #pragma unroll
      for (int kk = 0; kk < 2; ++kk) {
        const int row = 16 * nt + c;
        const int byte = row * 128 + ((64 * kk + 16 * g) ^ ((row & 7) << 4));
        const short8 bh = *(const short8*)(lds + OFF_MH + byte);
        const short8 bl = *(const short8*)(lds + OFF_ML + byte);
        a0 = MFMA(xh[0][kk], bh, a0);
        a0 = MFMA(xh[0][kk], bl, a0);
        a0 = MFMA(xl[0][kk], bh, a0);
        a1 = MFMA(xh[1][kk], bh, a1);
        a1 = MFMA(xh[1][kk], bl, a1);
        a1 = MFMA(xl[1][kk], bh, a1);
      }
      // D-frag: tmp[row=4g+j (+16)][col=16nt+c]. Store hi/lo (col within 32-half).
      #pragma unroll
      for (int j = 0; j < 4; ++j) {
        const int col2 = 2 * (16 * ntl + c);
        const int off0 = (4 * g + j) * PWSTR + col2;
        const int off1 = (16 + 4 * g + j) * PWSTR + col2;
        const unsigned short h0 = f2bf(a0[j]);
        *(unsigned short*)(wl + PW_RTH + off0) = h0;
        *(unsigned short*)(wl + PW_RTL + off0) = f2bf(a0[j] - bf2f(h0));
        const unsigned short h1 = f2bf(a1[j]);
        *(unsigned short*)(wl + PW_RTH + off1) = h1;
        *(unsigned short*)(wl + PW_RTL + off1) = f2bf(a1[j] - bf2f(h1));
      }
    }
    // read tmp back (same wave wrote -> in-order DS, no barrier)
    short8 tH[2], tL[2];
    #pragma unroll
    for (int i = 0; i < 2; ++i) {
      const int off = (16 * i + c) * PWSTR + 16 * g;
      tH[i] = *(const short8*)(wl + PW_RTH + off);
      tL[i] = *(const short8*)(wl + PW_RTL + off);
    }
    // P^T = X·tmp^T: A = x frag (k = d' chunk kt), B = tmp read (B[k][n]=tmp[n][k])
    #pragma unroll
    for (int mt = 0; mt < 2; ++mt) {
      #pragma unroll
      for (int nt2 = 0; nt2 < 2; ++nt2) {
        pa[mt][nt2] = MFMA(xh[mt][kt], tH[nt2], pa[mt][nt2]);
        pa[mt][nt2] = MFMA(xl[mt][kt], tH[nt2], pa[mt][nt2]);
        pa[mt][nt2] = MFMA(xh[mt][kt], tL[nt2], pa[mt][nt2]);
      }
    }
  }

  // ---- softmax on P^T frags: pa[mt][nt][j] = P[t=16nt+c][s=16mt+4g+j] ----
  char* const pbuf = wl + PW_P;
  #pragma unroll
  for (int nt = 0; nt < 2; ++nt) {
    const int t = 16 * nt + c;
    float v[8];
    #pragma unroll
    for (int mt = 0; mt < 2; ++mt)
      #pragma unroll
      for (int j = 0; j < 4; ++j) {
        const int s = 16 * mt + 4 * g + j;
        v[4 * mt + j] = (s <= t) ? pa[mt][nt][j] : -__builtin_inff();
      }
    float m = fmaxf(fmaxf(fmaxf(v[0], v[1]), fmaxf(v[2], v[3])),
                    fmaxf(fmaxf(v[4], v[5]), fmaxf(v[6], v[7])));
    m = fmaxf(m, __shfl_xor(m, 16));
    m = fmaxf(m, __shfl_xor(m, 32));
    float e[8], ssum = 0.f;
    #pragma unroll
    for (int i = 0; i < 8; ++i) { e[i] = exp2f(v[i] - m); ssum += e[i]; }
    ssum += __shfl_xor(ssum, 16);
    ssum += __shfl_xor(ssum, 32);
    const float r = __builtin_amdgcn_rcpf(ssum);
    #pragma unroll
    for (int mt = 0; mt < 2; ++mt) {
      const u32x2 w2 = {pk2(e[4 * mt] * r, e[4 * mt + 1] * r),
                        pk2(e[4 * mt + 2] * r, e[4 * mt + 3] * r)};
      *(u32x2*)(pbuf + t * 64 + 32 * mt + 8 * g) = w2;   // P[t][16mt+4g..+3]
    }
  }

  // ---- v = X·Wv (single term), stored transposed vT[h][s] (aliases rt) ----
  #pragma unroll
  for (int nt = 0; nt < 4; ++nt) {
    f32x4 a0 = {0.f, 0.f, 0.f, 0.f};
    f32x4 a1 = {0.f, 0.f, 0.f, 0.f};
    #pragma unroll
    for (int kk = 0; kk < 2; ++kk) {
      const int row = 16 * nt + c;
      const int byte = row * 128 + ((64 * kk + 16 * g) ^ ((row & 7) << 4));
      const short8 bv = *(const short8*)(lds + OFF_WV + byte);
      a0 = MFMA(xh[0][kk], bv, a0);
      a1 = MFMA(xh[1][kk], bv, a1);
    }
    // a0[j] = V[s=4g+j][h=16nt+c]; a1[j] = V[16+4g+j][h]. Pack along s.
    char* const vrow = wl + PW_VT + (16 * nt + c) * PWSTR;
    const u32x2 w0 = {pk2(a0[0], a0[1]), pk2(a0[2], a0[3])};
    const u32x2 w1 = {pk2(a1[0], a1[1]), pk2(a1[2], a1[3])};
    *(u32x2*)(vrow + 8 * g)      = w0;
    *(u32x2*)(vrow + 32 + 8 * g) = w1;
  }

  // ---- O^T = V^T·P^T (K = 32): A = vT A-frag, B = P A-layout read ----
  const short8 ap0 = *(const short8*)(pbuf + c * 64 + 16 * g);          // t = c
  const short8 ap1 = *(const short8*)(pbuf + (16 + c) * 64 + 16 * g);   // t = 16+c
  #pragma unroll
  for (int mh = 0; mh < 4; ++mh) {
    const short8 bv = *(const short8*)(wl + PW_VT + (16 * mh + c) * PWSTR + 16 * g);
    f32x4 o0 = {0.f, 0.f, 0.f, 0.f};
    f32x4 o1 = {0.f, 0.f, 0.f, 0.f};
    o0 = MFMA(bv, ap0, o0);   // D[m=h][n=t] = O^T
    o1 = MFMA(bv, ap1, o1);
    // o0[j] = O[t=c][h=16mh+4g+j] -> contiguous dwordx4
    *(f32x4*)(ob + c * NH + 16 * mh + 4 * g)        = o0;
    *(f32x4*)(ob + (16 + c) * NH + 16 * mh + 4 * g) = o1;
  }
}

__global__ __launch_bounds__(256, 3) void head_fused(
    const float* __restrict__ x,
    const unsigned short* __restrict__ MtH, const unsigned short* __restrict__ MtL,
    const unsigned short* __restrict__ WvT,
    float* __restrict__ out, int wstride)
{
  __shared__ __align__(16) char lds[LDS_BYTES];
  const int tid = threadIdx.x;

  // ---- stage Mt hi/lo + WvT (u32 swizzled copies from ws) ----
  {
    const unsigned int* srcH = (const unsigned int*)MtH;
    const unsigned int* srcL = (const unsigned int*)MtL;
    const unsigned int* srcV = (const unsigned int*)WvT;
    #pragma unroll
    for (int i = 0; i < 8; ++i) {
      const int e = tid + 256 * i;            // u32 index [0,2048)
      const int row = e >> 5;
      const int byte = row * 128 + (((e & 31) * 4) ^ ((row & 7) << 4));
      *(unsigned int*)(lds + OFF_MH + byte) = srcH[e];
      *(unsigned int*)(lds + OFF_ML + byte) = srcL[e];
      *(unsigned int*)(lds + OFF_WV + byte) = srcV[e];
    }
  }
  __syncthreads();

  const int wid  = tid >> 6;
  const int lane = tid & 63;
  const int c = lane & 15;
  const int g = lane >> 4;
  char* const wl = lds + OFF_WAVE + wid * WAVE_BYTES;

  const int w = blockIdx.x * 4 + wid;         // [0, wstride)

  f32x4 xc[2][2][2];
  load_x(x + (long)w * (CTX * ND), xc, c, g);

  #pragma unroll
  for (int it = 0; it < NB_PER_WAVE; ++it) {
    const long b = (long)w + (long)it * wstride;
    f32x4 xn[2][2][2];
    if (it + 1 < NB_PER_WAVE)
      load_x(x + (b + wstride) * (CTX * ND), xn, c, g);   // prefetch, overlaps compute
    compute_batch(xc, lds, wl, out + b * (CTX * NH), c, g);
    if (it + 1 < NB_PER_WAVE) {
      #pragma unroll
      for (int i = 0; i < 2; ++i)
        #pragma unroll
        for (int k = 0; k < 2; ++k)
          #pragma unroll
          for (int h = 0; h < 2; ++h) xc[i][k][h] = xn[i][k][h];
    }
  }
}

extern "C" void kernel_launch(void* const* d_in, const int* in_sizes, int n_in,
                              void* d_out, int out_size, void* d_ws, size_t ws_size,
                              hipStream_t stream) {
  // setup_inputs order: x, Wk, Wq, Wv  (all fp32)
  const float* x  = (const float*)d_in[0];
  const float* Wk = (const float*)d_in[1];
  const float* Wq = (const float*)d_in[2];
  const float* Wv = (const float*)d_in[3];
  float* out = (float*)d_out;

  unsigned short* MtH = (unsigned short*)d_ws;          // [64][64] bf16
  unsigned short* MtL = MtH + 64 * 64;
  unsigned short* WvT = MtL + 64 * 64;

  mk_m<<<dim3(16), dim3(256), 0, stream>>>(Wq, Wk, Wv, MtH, MtL, WvT);

  const int batch = in_sizes[0] / (CTX * ND);           // 16384
  const int wstride = batch / NB_PER_WAVE;              // 8192 waves
  head_fused<<<dim3(wstride / 4), dim3(256), 0, stream>>>(x, MtH, MtL, WvT, out, wstride);
}